// Round 1
// baseline (462.603 us; speedup 1.0000x reference)
//
#include <hip/hip_runtime.h>
#include <hip/hip_bf16.h>

#define NN 8192
#define INC 128
#define OUTC 64

typedef __attribute__((ext_vector_type(8))) short bf16x8;
typedef __attribute__((ext_vector_type(4))) float f32x4;
typedef __attribute__((ext_vector_type(4))) int i32x4;

static __device__ __forceinline__ unsigned short f2bf(float x) {
    unsigned int u = __builtin_bit_cast(unsigned int, x);
    u += 0x7fffu + ((u >> 16) & 1u);   // RNE, x is always finite here
    return (unsigned short)(u >> 16);
}
static __device__ __forceinline__ float bf2f(unsigned short b) {
    unsigned int u = ((unsigned int)b) << 16;
    return __builtin_bit_cast(float, u);
}

// ---------------------------------------------------------------------------
// K1: Wh = h @ W  (write bf16 TRANSPOSED: whbt[ch][row]),  f = Wh@a1, g = Wh@a2
// One wave = one row (64 lanes = 64 output channels).
// ---------------------------------------------------------------------------
__global__ __launch_bounds__(256) void k1_wh(const float* __restrict__ h,
                                             const float* __restrict__ W,
                                             const float* __restrict__ a,
                                             unsigned short* __restrict__ whbt,
                                             float* __restrict__ f,
                                             float* __restrict__ g)
{
    const int gid = blockIdx.x * 256 + threadIdx.x;
    const int row = gid >> 6;
    const int ch  = gid & 63;
    const f32x4* h4 = (const f32x4*)(h + (size_t)row * INC);
    float acc = 0.f;
#pragma unroll 8
    for (int k4 = 0; k4 < INC / 4; ++k4) {
        f32x4 hv = h4[k4];
        acc += hv[0] * W[(k4 * 4 + 0) * OUTC + ch];
        acc += hv[1] * W[(k4 * 4 + 1) * OUTC + ch];
        acc += hv[2] * W[(k4 * 4 + 2) * OUTC + ch];
        acc += hv[3] * W[(k4 * 4 + 3) * OUTC + ch];
    }
    whbt[(size_t)ch * NN + row] = f2bf(acc);

    float v1 = acc * a[ch];
    float v2 = acc * a[64 + ch];
#pragma unroll
    for (int m = 1; m < 64; m <<= 1) {
        v1 += __shfl_xor(v1, m, 64);
        v2 += __shfl_xor(v2, m, 64);
    }
    if ((threadIdx.x & 63) == 0) {
        f[row] = v1;
        g[row] = v2;
    }
}

// ---------------------------------------------------------------------------
// K2: global max of g (analytic softmax bound)
// ---------------------------------------------------------------------------
__global__ __launch_bounds__(256) void k2_gmax(const float* __restrict__ g,
                                               float* __restrict__ gmax)
{
    __shared__ float red[256];
    float m = -1e30f;
    for (int i = threadIdx.x; i < NN; i += 256) m = fmaxf(m, g[i]);
    red[threadIdx.x] = m;
    __syncthreads();
    for (int s = 128; s > 0; s >>= 1) {
        if ((int)threadIdx.x < s) red[threadIdx.x] = fmaxf(red[threadIdx.x], red[threadIdx.x + s]);
        __syncthreads();
    }
    if (threadIdx.x == 0) *gmax = red[0];
}

// ---------------------------------------------------------------------------
// K3: flash-style masked-softmax-weighted accumulation.
// Block = 4 waves; wave = 16 rows (MFMA M=16); 32 cols per step.
// blockIdx.y = j-chunk (partials combined in K4).
// Per lane per step: 8 adj ints + 8 g + 4 B-fragments; P built in registers
// directly in A-fragment layout (row = lane&15, k = (lane>>4)*8 + t).
// ---------------------------------------------------------------------------
__global__ __launch_bounds__(256) void k3_attn(const int* __restrict__ adj,
                                               const unsigned short* __restrict__ whbt,
                                               const float* __restrict__ f,
                                               const float* __restrict__ g,
                                               const float* __restrict__ gmaxp,
                                               float* __restrict__ accP,
                                               float* __restrict__ lP,
                                               int colsPerChunk)
{
    const int lane = threadIdx.x & 63;
    const int wave = threadIdx.x >> 6;
    const int lr16 = lane & 15;
    const int kg   = lane >> 4;
    const int rowBase = blockIdx.x * 64 + wave * 16;
    const int r = rowBase + lr16;
    const int chunk = blockIdx.y;
    const int jStart = chunk * colsPerChunk;

    const float L2E = 1.4426950408889634f;
    const float fr = f[r];
    const float gmax = *gmaxp;
    float mm = fr + gmax;
    mm = fmaxf(mm, 0.5f * mm);          // LeakyReLU(f_r + gmax) >= all scores in row
    const float mL = mm * L2E;

    f32x4 acc0 = {0.f, 0.f, 0.f, 0.f};
    f32x4 acc1 = {0.f, 0.f, 0.f, 0.f};
    f32x4 acc2 = {0.f, 0.f, 0.f, 0.f};
    f32x4 acc3 = {0.f, 0.f, 0.f, 0.f};
    float ls = 0.f;

    const int* adjRow = adj + (size_t)r * NN;
    const unsigned short* wb0 = whbt + (size_t)(0 * 16 + lr16) * NN;
    const unsigned short* wb1 = whbt + (size_t)(1 * 16 + lr16) * NN;
    const unsigned short* wb2 = whbt + (size_t)(2 * 16 + lr16) * NN;
    const unsigned short* wb3 = whbt + (size_t)(3 * 16 + lr16) * NN;

    for (int j0 = jStart; j0 < jStart + colsPerChunk; j0 += 32) {
        const int jl = j0 + kg * 8;
        i32x4 ad0 = *(const i32x4*)(adjRow + jl);
        i32x4 ad1 = *(const i32x4*)(adjRow + jl + 4);
        f32x4 g0  = *(const f32x4*)(g + jl);
        f32x4 g1  = *(const f32x4*)(g + jl + 4);
        bf16x8 b0 = *(const bf16x8*)(wb0 + jl);
        bf16x8 b1 = *(const bf16x8*)(wb1 + jl);
        bf16x8 b2 = *(const bf16x8*)(wb2 + jl);
        bf16x8 b3 = *(const bf16x8*)(wb3 + jl);

        bf16x8 af;
#pragma unroll
        for (int t = 0; t < 8; ++t) {
            float gj = (t < 4) ? g0[t] : g1[t - 4];
            int   ad = (t < 4) ? ad0[t] : ad1[t - 4];
            float s  = fr + gj;
            float lr = fmaxf(s, 0.5f * s);                       // LeakyReLU, alpha=0.5
            float w  = __builtin_amdgcn_exp2f(lr * L2E - mL);    // <= 1
            w = (ad > 0) ? w : 0.f;
            unsigned short b = f2bf(w);
            af[t] = (short)b;
            ls += bf2f(b);      // row-sum from the SAME bf16-rounded weights
        }
        acc0 = __builtin_amdgcn_mfma_f32_16x16x32_bf16(af, b0, acc0, 0, 0, 0);
        acc1 = __builtin_amdgcn_mfma_f32_16x16x32_bf16(af, b1, acc1, 0, 0, 0);
        acc2 = __builtin_amdgcn_mfma_f32_16x16x32_bf16(af, b2, acc2, 0, 0, 0);
        acc3 = __builtin_amdgcn_mfma_f32_16x16x32_bf16(af, b3, acc3, 0, 0, 0);
    }

    // combine the 4 k-group partial row sums (lanes l, l^16, l^32, l^48 share a row)
    ls += __shfl_xor(ls, 16, 64);
    ls += __shfl_xor(ls, 32, 64);
    if (lane < 16) lP[(size_t)chunk * NN + rowBase + lane] = ls;

    // D layout: col = lane&15 (n within 16-slice), row = (lane>>4)*4 + q
    float* ap = accP + (size_t)chunk * NN * OUTC;
#pragma unroll
    for (int q = 0; q < 4; ++q) {
        const int rm = rowBase + kg * 4 + q;
        ap[(size_t)rm * OUTC +  0 + lr16] = acc0[q];
        ap[(size_t)rm * OUTC + 16 + lr16] = acc1[q];
        ap[(size_t)rm * OUTC + 32 + lr16] = acc2[q];
        ap[(size_t)rm * OUTC + 48 + lr16] = acc3[q];
    }
}

// ---------------------------------------------------------------------------
// K4: combine j-chunk partials, normalize, final LeakyReLU
// ---------------------------------------------------------------------------
__global__ __launch_bounds__(256) void k4_final(const float* __restrict__ accP,
                                                const float* __restrict__ lP,
                                                float* __restrict__ out, int js)
{
    const int gid = blockIdx.x * 256 + threadIdx.x;
    const int row = gid >> 6;
    const int ch  = gid & 63;
    float av = 0.f, lv = 0.f;
    for (int c = 0; c < js; ++c) {
        av += accP[((size_t)c * NN + row) * OUTC + ch];
        lv += lP[(size_t)c * NN + row];
    }
    if (lv == 0.f) lv = 1.f;            // unreachable for this data; NaN guard
    const float hv = av / lv;
    out[(size_t)row * OUTC + ch] = fmaxf(hv, 0.5f * hv);
}

extern "C" void kernel_launch(void* const* d_in, const int* in_sizes, int n_in,
                              void* d_out, int out_size, void* d_ws, size_t ws_size,
                              hipStream_t stream)
{
    const float* h   = (const float*)d_in[0];
    const int*   adj = (const int*)d_in[1];
    const float* W   = (const float*)d_in[2];
    const float* a   = (const float*)d_in[3];
    float* out = (float*)d_out;

    char* ws = (char*)d_ws;
    unsigned short* whbt = (unsigned short*)ws;
    size_t off = (size_t)OUTC * NN * sizeof(unsigned short);   // 1 MB
    float* f = (float*)(ws + off); off += (size_t)NN * 4;
    float* g = (float*)(ws + off); off += (size_t)NN * 4;
    float* gmax = (float*)(ws + off); off += 256;

    const size_t perChunk = (size_t)NN * OUTC * 4 + (size_t)NN * 4;
    int js = 8;
    while (js > 1 && off + (size_t)js * perChunk > ws_size) js >>= 1;
    float* accP = (float*)(ws + off); off += (size_t)js * NN * OUTC * 4;
    float* lP   = (float*)(ws + off);

    k1_wh<<<dim3(NN * OUTC / 256), 256, 0, stream>>>(h, W, a, whbt, f, g);
    k2_gmax<<<1, 256, 0, stream>>>(g, gmax);
    const int colsPerChunk = NN / js;
    k3_attn<<<dim3(NN / 64, js), 256, 0, stream>>>(adj, whbt, f, g, gmax, accP, lP, colsPerChunk);
    k4_final<<<dim3(NN * OUTC / 256), 256, 0, stream>>>(accP, lP, out, js);
}